// Round 2
// baseline (18215.263 us; speedup 1.0000x reference)
//
#include <hip/hip_runtime.h>
#include <hip/hip_fp16.h>

#define HD 128
#define G4 512
#define TT 168
#define OUTH 24
#define NB 4096
#define RPB 16

typedef struct __align__(16) { __half2 a, b, c, d; } H8;

__device__ __forceinline__ float tanh_f(float x) {
  float e = __expf(2.f * x);
  return 1.f - 2.f / (e + 1.f);
}
__device__ __forceinline__ float sigm_f(float x) {
  float e = __expf(-x);
  return 1.f / (1.f + e);
}

// ---------------- K0: weight prep (transposes + fused biases) ----------------
__global__ void prep_kernel(const float* __restrict__ enc_Whh,
                            const float* __restrict__ enc_bih, const float* __restrict__ enc_bhh,
                            const float* __restrict__ Wa, const float* __restrict__ Ua,
                            const float* __restrict__ dec_Wih, const float* __restrict__ dec_Whh,
                            const float* __restrict__ dec_bih, const float* __restrict__ dec_bhh,
                            float* __restrict__ WhhT, float* __restrict__ bias_e,
                            float* __restrict__ WdT, float* __restrict__ bias_d,
                            float* __restrict__ WaT, float* __restrict__ UaT) {
  int tid = blockIdx.x * blockDim.x + threadIdx.x;
  int nt = gridDim.x * blockDim.x;
  for (int i = tid; i < HD * G4; i += nt) { int k = i / G4, g = i % G4; WhhT[i] = enc_Whh[g * HD + k]; }
  for (int i = tid; i < G4; i += nt) { bias_e[i] = enc_bih[i] + enc_bhh[i]; bias_d[i] = dec_bih[i] + dec_bhh[i]; }
  for (int i = tid; i < 257 * G4; i += nt) {
    int k = i / G4, g = i % G4;
    WdT[i] = (k < 129) ? dec_Wih[g * 129 + k] : dec_Whh[g * HD + (k - 129)];
  }
  for (int i = tid; i < HD * HD; i += nt) { int k = i / HD, j = i % HD; WaT[i] = Wa[j * HD + k]; UaT[i] = Ua[j * HD + k]; }
}

// ---------------- K1: encoder LSTM, 16 rows/block, 168 steps in-kernel ----------------
// All pointers are chunk-local (host offsets them). rbase is within-chunk.
__global__ __launch_bounds__(512)
void enc_kernel(const float* __restrict__ x, const float* __restrict__ enc_Wih,
                const float* __restrict__ WhhT, const float* __restrict__ bias_e,
                __half* __restrict__ enc_f16, float* __restrict__ hn, float* __restrict__ cn) {
  __shared__ float xs[RPB][TT];
  __shared__ float hs[HD][RPB];
  __shared__ float cs[RPB][HD];
  __shared__ float gs[G4][17];
  const int tid = threadIdx.x;
  const int g = tid;
  const int rbase = blockIdx.x * RPB;
  for (int i = tid; i < RPB * TT; i += 512) xs[i / TT][i % TT] = x[(size_t)rbase * TT + i];
  for (int i = tid; i < HD * RPB; i += 512) hs[i >> 4][i & 15] = 0.f;
  for (int i = tid; i < RPB * HD; i += 512) cs[i >> 7][i & 127] = 0.f;
  const float wih = enc_Wih[g];
  const float bias = bias_e[g];
  const int gty = g >> 7;  // 0:i 1:f 2:g 3:o
  const int hidx = tid & 127;
  const int rq = tid >> 7;
  __syncthreads();
  for (int t = 0; t < TT; ++t) {
    float acc[RPB];
#pragma unroll
    for (int r = 0; r < RPB; ++r) acc[r] = fmaf(xs[r][t], wih, bias);
#pragma unroll 2
    for (int k = 0; k < HD; ++k) {
      float w = WhhT[k * G4 + g];
      float hv[RPB];
      *(float4*)&hv[0]  = *(const float4*)&hs[k][0];
      *(float4*)&hv[4]  = *(const float4*)&hs[k][4];
      *(float4*)&hv[8]  = *(const float4*)&hs[k][8];
      *(float4*)&hv[12] = *(const float4*)&hs[k][12];
#pragma unroll
      for (int r = 0; r < RPB; ++r) acc[r] = fmaf(hv[r], w, acc[r]);
    }
#pragma unroll
    for (int r = 0; r < RPB; ++r) gs[g][r] = (gty == 2) ? tanh_f(acc[r]) : sigm_f(acc[r]);
    __syncthreads();
#pragma unroll
    for (int rr = 0; rr < 4; ++rr) {
      int r = rq * 4 + rr;
      float iv = gs[hidx][r], fv = gs[128 + hidx][r], gv = gs[256 + hidx][r], ov = gs[384 + hidx][r];
      float c = fmaf(fv, cs[r][hidx], iv * gv);
      cs[r][hidx] = c;
      float h = ov * tanh_f(c);
      hs[hidx][r] = h;
      enc_f16[((size_t)(rbase + r) * TT + t) * HD + hidx] = __float2half(h);
    }
    __syncthreads();
  }
#pragma unroll
  for (int rr = 0; rr < 4; ++rr) {
    int r = rq * 4 + rr;
    hn[(size_t)(rbase + r) * HD + hidx] = hs[hidx][r];
    cn[(size_t)(rbase + r) * HD + hidx] = cs[r][hidx];
  }
}

// ---------------- K2: Ue = enc @ Ua^T  (rows x 128 x 128), fp32 accum ----------------
__global__ __launch_bounds__(256)
void ue_kernel(const __half* __restrict__ enc_f16, const float* __restrict__ UaT,
               __half* __restrict__ Ue) {
  __shared__ float es[HD][68];  // transposed tile [k][row], 64 rows
  const int tid = threadIdx.x;
  const int j = tid & 127, rh = tid >> 7;
  const size_t nbase = (size_t)blockIdx.x * 64;
  for (int i = tid; i < 64 * 64; i += 256) {
    int row = i >> 6, k2 = i & 63;
    __half2 hv = ((const __half2*)enc_f16)[(nbase + row) * 64 + k2];
    float2 f = __half22float2(hv);
    es[2 * k2][row] = f.x;
    es[2 * k2 + 1][row] = f.y;
  }
  __syncthreads();
  float acc[32];
#pragma unroll
  for (int r = 0; r < 32; ++r) acc[r] = 0.f;
  const int rb = rh * 32;
  for (int k = 0; k < HD; ++k) {
    float w = UaT[k * HD + j];
    float ev[32];
#pragma unroll
    for (int q = 0; q < 8; ++q) *(float4*)&ev[q * 4] = *(const float4*)&es[k][rb + q * 4];
#pragma unroll
    for (int r = 0; r < 32; ++r) acc[r] = fmaf(ev[r], w, acc[r]);
  }
#pragma unroll
  for (int r = 0; r < 32; ++r) Ue[(nbase + rb + r) * HD + j] = __float2half(acc[r]);
}

// ---------------- K3: decoder, 16 rows/block, 24 steps in-kernel ----------------
__global__ __launch_bounds__(512)
void dec_kernel(const float* __restrict__ x, const __half* __restrict__ enc_f16,
                const __half* __restrict__ Ue,
                const float* __restrict__ hn, const float* __restrict__ cn,
                const float* __restrict__ WaT, const float* __restrict__ va,
                const float* __restrict__ WdT, const float* __restrict__ bias_d,
                const float* __restrict__ fc_W, const float* __restrict__ fc_b,
                float* __restrict__ out) {
  __shared__ float inp[257][20];
  __shared__ float cs[RPB][HD];
  __shared__ float ppart[RPB][2];
  __shared__ float upool[G4 * 17];
  float (*qsh)[HD] = (float(*)[HD])upool;
  float (*ssh)[TT] = (float(*)[TT])(upool + RPB * HD);
  float (*gsh)[17] = (float(*)[17])upool;

  const int tid = threadIdx.x;
  const int rbase = blockIdx.x * RPB;
  const int jq = tid & 3, tl = tid >> 2;      // attention mapping
  const int hidx = tid & 127, rq = tid >> 7;  // q / cell mapping
  const int g = tid;                          // gates mapping
  const int gty = g >> 7;
  const float biasd = bias_d[g];
  const float fcw = fc_W[hidx];
  const float fcb = fc_b[0];
  float vr[32];
#pragma unroll
  for (int i = 0; i < 32; ++i) vr[i] = va[jq * 32 + i];

  for (int i = tid; i < RPB * HD; i += 512) {
    int r = i >> 7, k = i & 127;
    inp[129 + k][r] = hn[(size_t)(rbase + r) * HD + k];
    cs[r][k] = cn[(size_t)(rbase + r) * HD + k];
  }
  if (tid < RPB) inp[0][tid] = x[(size_t)(rbase + tid) * TT + (TT - 1)];
  __syncthreads();

  for (int s = 0; s < OUTH; ++s) {
    // (a) q = h @ Wa^T
    {
      float qa[4] = {0.f, 0.f, 0.f, 0.f};
      for (int k = 0; k < HD; ++k) {
        float w = WaT[k * HD + hidx];
        float4 hv = *(const float4*)&inp[129 + k][rq * 4];
        qa[0] = fmaf(hv.x, w, qa[0]);
        qa[1] = fmaf(hv.y, w, qa[1]);
        qa[2] = fmaf(hv.z, w, qa[2]);
        qa[3] = fmaf(hv.w, w, qa[3]);
      }
#pragma unroll
      for (int rr = 0; rr < 4; ++rr) qsh[rq * 4 + rr][hidx] = qa[rr];
    }
    __syncthreads();
    // (b) scores[r][t] = sum_j v_j * tanh(Ue[r][t][j] + q[r][j])
    for (int r = 0; r < RPB; ++r) {
      float qr[32];
#pragma unroll
      for (int q4 = 0; q4 < 8; ++q4) *(float4*)&qr[q4 * 4] = *(const float4*)&qsh[r][jq * 32 + q4 * 4];
      const __half* Uep = Ue + ((size_t)(rbase + r) * TT) * HD + jq * 32;
#pragma unroll
      for (int i2 = 0; i2 < 2; ++i2) {
        int t = tl + i2 * 128;
        if (t < TT) {
          const H8* up = (const H8*)(Uep + (size_t)t * HD);
          float sp = 0.f;
#pragma unroll
          for (int c8 = 0; c8 < 4; ++c8) {
            H8 hv = up[c8];
            float2 f0 = __half22float2(hv.a);
            float2 f1 = __half22float2(hv.b);
            float2 f2 = __half22float2(hv.c);
            float2 f3 = __half22float2(hv.d);
            int b0 = c8 * 8;
            sp = fmaf(tanh_f(f0.x + qr[b0 + 0]), vr[b0 + 0], sp);
            sp = fmaf(tanh_f(f0.y + qr[b0 + 1]), vr[b0 + 1], sp);
            sp = fmaf(tanh_f(f1.x + qr[b0 + 2]), vr[b0 + 2], sp);
            sp = fmaf(tanh_f(f1.y + qr[b0 + 3]), vr[b0 + 3], sp);
            sp = fmaf(tanh_f(f2.x + qr[b0 + 4]), vr[b0 + 4], sp);
            sp = fmaf(tanh_f(f2.y + qr[b0 + 5]), vr[b0 + 5], sp);
            sp = fmaf(tanh_f(f3.x + qr[b0 + 6]), vr[b0 + 6], sp);
            sp = fmaf(tanh_f(f3.y + qr[b0 + 7]), vr[b0 + 7], sp);
          }
          sp += __shfl_xor(sp, 1);
          sp += __shfl_xor(sp, 2);
          if (jq == 0) ssh[r][t] = sp;
        }
      }
    }
    __syncthreads();
    // (c) softmax over t per row (32 lanes per row)
    {
      int r = tid >> 5, l = tid & 31;
      float m = -1e30f;
      for (int t = l; t < TT; t += 32) m = fmaxf(m, ssh[r][t]);
#pragma unroll
      for (int o = 1; o < 32; o <<= 1) m = fmaxf(m, __shfl_xor(m, o, 32));
      float se = 0.f;
      for (int t = l; t < TT; t += 32) { float e = __expf(ssh[r][t] - m); ssh[r][t] = e; se += e; }
#pragma unroll
      for (int o = 1; o < 32; o <<= 1) se += __shfl_xor(se, o, 32);
      float inv = 1.f / se;
      for (int t = l; t < TT; t += 32) ssh[r][t] *= inv;
    }
    __syncthreads();
    // (d) context[r][j] = sum_t attn * enc
    {
      int jp = tid & 63, rs = tid >> 6;
#pragma unroll
      for (int rr = 0; rr < 2; ++rr) {
        int r = rs + rr * 8;
        const __half2* ep = (const __half2*)(enc_f16 + ((size_t)(rbase + r) * TT) * HD) + jp;
        float c0 = 0.f, c1 = 0.f;
#pragma unroll 4
        for (int t = 0; t < TT; ++t) {
          float a = ssh[r][t];
          float2 ef = __half22float2(ep[(size_t)t * 64]);
          c0 = fmaf(a, ef.x, c0);
          c1 = fmaf(a, ef.y, c1);
        }
        inp[1 + 2 * jp][r] = c0;
        inp[2 + 2 * jp][r] = c1;
      }
    }
    __syncthreads();
    // (e) gates = [din|ctx|h] @ WdT + bias
    {
      float acc[RPB];
#pragma unroll
      for (int r = 0; r < RPB; ++r) acc[r] = biasd;
#pragma unroll 2
      for (int k = 0; k < 257; ++k) {
        float w = WdT[k * G4 + g];
        float iv[RPB];
        *(float4*)&iv[0]  = *(const float4*)&inp[k][0];
        *(float4*)&iv[4]  = *(const float4*)&inp[k][4];
        *(float4*)&iv[8]  = *(const float4*)&inp[k][8];
        *(float4*)&iv[12] = *(const float4*)&inp[k][12];
#pragma unroll
        for (int r = 0; r < RPB; ++r) acc[r] = fmaf(iv[r], w, acc[r]);
      }
#pragma unroll
      for (int r = 0; r < RPB; ++r) gsh[g][r] = (gty == 2) ? tanh_f(acc[r]) : sigm_f(acc[r]);
    }
    __syncthreads();
    // (f) cell update + pred
    {
      float pp[4];
#pragma unroll
      for (int rr = 0; rr < 4; ++rr) {
        int r = rq * 4 + rr;
        float iv = gsh[hidx][r], fv = gsh[128 + hidx][r], gv = gsh[256 + hidx][r], ov = gsh[384 + hidx][r];
        float c = fmaf(fv, cs[r][hidx], iv * gv);
        cs[r][hidx] = c;
        float h2 = ov * tanh_f(c);
        inp[129 + hidx][r] = h2;
        pp[rr] = h2 * fcw;
      }
#pragma unroll
      for (int rr = 0; rr < 4; ++rr) {
        float sv = pp[rr];
#pragma unroll
        for (int o = 1; o < 64; o <<= 1) sv += __shfl_xor(sv, o);
        if ((tid & 63) == 0) ppart[rq * 4 + rr][(tid >> 6) & 1] = sv;
      }
    }
    __syncthreads();
    if (tid < RPB) {
      float pred = ppart[tid][0] + ppart[tid][1] + fcb;
      out[(size_t)(rbase + tid) * OUTH + s] = pred;
      inp[0][tid] = pred;
    }
    __syncthreads();
  }
}

extern "C" void kernel_launch(void* const* d_in, const int* in_sizes, int n_in,
                              void* d_out, int out_size, void* d_ws, size_t ws_size,
                              hipStream_t stream) {
  const float* x       = (const float*)d_in[0];
  const float* enc_Wih = (const float*)d_in[1];
  const float* enc_Whh = (const float*)d_in[2];
  const float* enc_bih = (const float*)d_in[3];
  const float* enc_bhh = (const float*)d_in[4];
  const float* Wa      = (const float*)d_in[5];
  const float* Ua      = (const float*)d_in[6];
  const float* va      = (const float*)d_in[7];
  const float* dec_Wih = (const float*)d_in[8];
  const float* dec_Whh = (const float*)d_in[9];
  const float* dec_bih = (const float*)d_in[10];
  const float* dec_bhh = (const float*)d_in[11];
  const float* fc_W    = (const float*)d_in[12];
  const float* fc_b    = (const float*)d_in[13];
  float* out = (float*)d_out;

  char* ws = (char*)d_ws;
  size_t off = 0;
  float* WhhT = (float*)(ws + off); off += (size_t)HD * G4 * 4;
  float* be   = (float*)(ws + off); off += (size_t)G4 * 4;
  float* WdT  = (float*)(ws + off); off += (size_t)257 * G4 * 4;
  float* bd   = (float*)(ws + off); off += (size_t)G4 * 4;
  float* WaT  = (float*)(ws + off); off += (size_t)HD * HD * 4;
  float* UaT  = (float*)(ws + off); off += (size_t)HD * HD * 4;
  float* hn   = (float*)(ws + off); off += (size_t)NB * HD * 4;
  float* cn   = (float*)(ws + off); off += (size_t)NB * HD * 4;
  // adaptive chunk plan: enc chunk CE rows, dec/ue chunk CD rows
  const size_t rowB = (size_t)TT * HD * 2;  // 43008 B per row (fp16)
  size_t avail = (ws_size > off) ? ws_size - off : 0;
  int CE, CD;
  if (avail >= 2 * (size_t)NB * rowB) {
    CE = NB; CD = NB;
  } else if (avail >= (size_t)NB * rowB + 16 * rowB) {
    CE = NB;
    CD = NB;
    while (CD > 16 && (size_t)NB * rowB + (size_t)CD * rowB > avail) CD >>= 1;
  } else {
    int c = NB;
    while (c > 16 && 2 * (size_t)c * rowB > avail) c >>= 1;
    if (2 * (size_t)c * rowB > avail) return;  // hopeless: <6.3MB scratch
    CE = CD = c;
  }
  __half* encb = (__half*)(ws + off);
  __half* ueb  = (__half*)(ws + off + (size_t)CE * rowB);

  prep_kernel<<<dim3(64), dim3(256), 0, stream>>>(enc_Whh, enc_bih, enc_bhh, Wa, Ua,
      dec_Wih, dec_Whh, dec_bih, dec_bhh, WhhT, be, WdT, bd, WaT, UaT);

  if (CE == NB) {
    enc_kernel<<<dim3(NB / RPB), dim3(512), 0, stream>>>(x, enc_Wih, WhhT, be, encb, hn, cn);
    for (int c0 = 0; c0 < NB; c0 += CD) {
      const __half* ec = encb + (size_t)c0 * TT * HD;
      ue_kernel<<<dim3(CD * TT / 64), dim3(256), 0, stream>>>(ec, UaT, ueb);
      dec_kernel<<<dim3(CD / RPB), dim3(512), 0, stream>>>(x + (size_t)c0 * TT, ec, ueb,
          hn + (size_t)c0 * HD, cn + (size_t)c0 * HD, WaT, va, WdT, bd, fc_W, fc_b,
          out + (size_t)c0 * OUTH);
    }
  } else {
    for (int c0 = 0; c0 < NB; c0 += CE) {
      enc_kernel<<<dim3(CE / RPB), dim3(512), 0, stream>>>(x + (size_t)c0 * TT, enc_Wih, WhhT, be,
          encb, hn + (size_t)c0 * HD, cn + (size_t)c0 * HD);
      ue_kernel<<<dim3(CE * TT / 64), dim3(256), 0, stream>>>(encb, UaT, ueb);
      dec_kernel<<<dim3(CE / RPB), dim3(512), 0, stream>>>(x + (size_t)c0 * TT, encb, ueb,
          hn + (size_t)c0 * HD, cn + (size_t)c0 * HD, WaT, va, WdT, bd, fc_W, fc_b,
          out + (size_t)c0 * OUTH);
    }
  }
}

// Round 3
// 8764.939 us; speedup vs baseline: 2.0782x; 2.0782x over previous
//
#include <hip/hip_runtime.h>
#include <hip/hip_fp16.h>

#define HD 128
#define G4 512
#define TT 168
#define OUTH 24
#define NB 4096
#define RPBE 8   // rows/block encoder
#define RPBD 4   // rows/block decoder

typedef struct __align__(16) { __half2 a, b, c, d; } H8;

__device__ __forceinline__ float tanh_f(float x) {
  float e = __expf(2.f * x);
  return 1.f - 2.f / (e + 1.f);
}
__device__ __forceinline__ float sigm_f(float x) {
  float e = __expf(-x);
  return 1.f / (1.f + e);
}

// ---------------- K0: weight prep (transposes + fused biases) ----------------
__global__ void prep_kernel(const float* __restrict__ enc_Whh,
                            const float* __restrict__ enc_bih, const float* __restrict__ enc_bhh,
                            const float* __restrict__ Wa, const float* __restrict__ Ua,
                            const float* __restrict__ dec_Wih, const float* __restrict__ dec_Whh,
                            const float* __restrict__ dec_bih, const float* __restrict__ dec_bhh,
                            float* __restrict__ WhhT, float* __restrict__ bias_e,
                            float* __restrict__ WdT, float* __restrict__ bias_d,
                            float* __restrict__ WaT, float* __restrict__ UaT) {
  int tid = blockIdx.x * blockDim.x + threadIdx.x;
  int nt = gridDim.x * blockDim.x;
  for (int i = tid; i < HD * G4; i += nt) { int k = i / G4, g = i % G4; WhhT[i] = enc_Whh[g * HD + k]; }
  for (int i = tid; i < G4; i += nt) { bias_e[i] = enc_bih[i] + enc_bhh[i]; bias_d[i] = dec_bih[i] + dec_bhh[i]; }
  for (int i = tid; i < 257 * G4; i += nt) {
    int k = i / G4, g = i % G4;
    WdT[i] = (k < 129) ? dec_Wih[g * 129 + k] : dec_Whh[g * HD + (k - 129)];
  }
  for (int i = tid; i < HD * HD; i += nt) { int k = i / HD, j = i % HD; WaT[i] = Wa[j * HD + k]; UaT[i] = Ua[j * HD + k]; }
}

// ---------------- K1: encoder LSTM, 8 rows/block ----------------
__global__ __launch_bounds__(512)
void enc_kernel(const float* __restrict__ x, const float* __restrict__ enc_Wih,
                const float* __restrict__ WhhT, const float* __restrict__ bias_e,
                __half* __restrict__ enc_f16, float* __restrict__ hn, float* __restrict__ cn) {
  __shared__ float xs[RPBE][TT];
  __shared__ float hs[HD][RPBE];
  __shared__ float cs[RPBE][HD];
  __shared__ float gs[G4][RPBE + 1];
  const int tid = threadIdx.x;
  const int g = tid;
  const int rbase = blockIdx.x * RPBE;
  for (int i = tid; i < RPBE * TT; i += 512) xs[i / TT][i % TT] = x[(size_t)rbase * TT + i];
  for (int i = tid; i < HD * RPBE; i += 512) hs[i >> 3][i & 7] = 0.f;
  for (int i = tid; i < RPBE * HD; i += 512) cs[i >> 7][i & 127] = 0.f;
  const float wih = enc_Wih[g];
  const float bias = bias_e[g];
  const int gty = g >> 7;  // 0:i 1:f 2:g 3:o
  const int hidx = tid & 127;
  const int rq = tid >> 7;
  __syncthreads();
  for (int t = 0; t < TT; ++t) {
    float acc[RPBE];
#pragma unroll
    for (int r = 0; r < RPBE; ++r) acc[r] = fmaf(xs[r][t], wih, bias);
#pragma unroll 4
    for (int k = 0; k < HD; ++k) {
      float w = WhhT[k * G4 + g];
      float hv[RPBE];
      *(float4*)&hv[0] = *(const float4*)&hs[k][0];
      *(float4*)&hv[4] = *(const float4*)&hs[k][4];
#pragma unroll
      for (int r = 0; r < RPBE; ++r) acc[r] = fmaf(hv[r], w, acc[r]);
    }
#pragma unroll
    for (int r = 0; r < RPBE; ++r) gs[g][r] = (gty == 2) ? tanh_f(acc[r]) : sigm_f(acc[r]);
    __syncthreads();
#pragma unroll
    for (int rr = 0; rr < 2; ++rr) {
      int r = rq * 2 + rr;
      float iv = gs[hidx][r], fv = gs[128 + hidx][r], gv = gs[256 + hidx][r], ov = gs[384 + hidx][r];
      float c = fmaf(fv, cs[r][hidx], iv * gv);
      cs[r][hidx] = c;
      float h = ov * tanh_f(c);
      hs[hidx][r] = h;
      enc_f16[((size_t)(rbase + r) * TT + t) * HD + hidx] = __float2half(h);
    }
    __syncthreads();
  }
#pragma unroll
  for (int rr = 0; rr < 2; ++rr) {
    int r = rq * 2 + rr;
    hn[(size_t)(rbase + r) * HD + hidx] = hs[hidx][r];
    cn[(size_t)(rbase + r) * HD + hidx] = cs[r][hidx];
  }
}

// ---------------- K2: Ue = enc @ Ua^T, fp32 accum ----------------
__global__ __launch_bounds__(256)
void ue_kernel(const __half* __restrict__ enc_f16, const float* __restrict__ UaT,
               __half* __restrict__ Ue) {
  __shared__ float es[HD][68];
  const int tid = threadIdx.x;
  const int j = tid & 127, rh = tid >> 7;
  const size_t nbase = (size_t)blockIdx.x * 64;
  for (int i = tid; i < 64 * 64; i += 256) {
    int row = i >> 6, k2 = i & 63;
    __half2 hv = ((const __half2*)enc_f16)[(nbase + row) * 64 + k2];
    float2 f = __half22float2(hv);
    es[2 * k2][row] = f.x;
    es[2 * k2 + 1][row] = f.y;
  }
  __syncthreads();
  float acc[32];
#pragma unroll
  for (int r = 0; r < 32; ++r) acc[r] = 0.f;
  const int rb = rh * 32;
  for (int k = 0; k < HD; ++k) {
    float w = UaT[k * HD + j];
    float ev[32];
#pragma unroll
    for (int q = 0; q < 8; ++q) *(float4*)&ev[q * 4] = *(const float4*)&es[k][rb + q * 4];
#pragma unroll
    for (int r = 0; r < 32; ++r) acc[r] = fmaf(ev[r], w, acc[r]);
  }
#pragma unroll
  for (int r = 0; r < 32; ++r) Ue[(nbase + rb + r) * HD + j] = __float2half(acc[r]);
}

// ---------------- K3: decoder, 4 rows/block, 24 steps in-kernel ----------------
__global__ __launch_bounds__(512)
void dec_kernel(const float* __restrict__ x, const __half* __restrict__ enc_f16,
                const __half* __restrict__ Ue,
                const float* __restrict__ hn, const float* __restrict__ cn,
                const float* __restrict__ WaT, const float* __restrict__ va,
                const float* __restrict__ WdT, const float* __restrict__ bias_d,
                const float* __restrict__ fc_W, const float* __restrict__ fc_b,
                float* __restrict__ out) {
  __shared__ float inp[257][8];          // k-major: [0]=din, [1..128]=ctx, [129..256]=h
  __shared__ float cs[RPBD][HD];
  __shared__ float ppart[RPBD][2];
  __shared__ float upool[G4 * 5];        // gates overlay
  float (*qsh)[HD] = (float(*)[HD])upool;                     // [4][128]
  float (*ssh)[TT] = (float(*)[TT])(upool + RPBD * HD);       // [4][168]
  float (*cpart)[RPBD][HD] = (float(*)[RPBD][HD])(upool + RPBD * HD + RPBD * TT);  // [2][4][128]
  float (*gsh)[5] = (float(*)[5])upool;                       // [512][5]

  const int tid = threadIdx.x;
  const int rbase = blockIdx.x * RPBD;
  const int jq = tid & 3, tl = tid >> 2;      // score mapping
  const int hidx = tid & 127, rq = tid >> 7;  // q / cell mapping (rq = row)
  const int g = tid;                          // gates mapping
  const int gty = g >> 7;
  const float biasd = bias_d[g];
  const float fcw = fc_W[hidx];
  const float fcb = fc_b[0];
  float vr[32];
#pragma unroll
  for (int i = 0; i < 32; ++i) vr[i] = va[jq * 32 + i];

  {
    int r = tid >> 7, k = tid & 127;
    inp[129 + k][r] = hn[(size_t)(rbase + r) * HD + k];
    cs[r][k] = cn[(size_t)(rbase + r) * HD + k];
  }
  if (tid < RPBD) inp[0][tid] = x[(size_t)(rbase + tid) * TT + (TT - 1)];
  __syncthreads();

  for (int s = 0; s < OUTH; ++s) {
    // (a) q[r] = h[r] @ Wa^T   (thread = (hidx, rq))
    {
      float qa = 0.f;
      for (int k = 0; k < HD; ++k) qa = fmaf(inp[129 + k][rq], WaT[k * HD + hidx], qa);
      qsh[rq][hidx] = qa;
    }
    __syncthreads();
    // (b) scores[r][t] = sum_j v_j * tanh(Ue[r][t][j] + q[r][j])
#pragma unroll
    for (int r = 0; r < RPBD; ++r) {
      float qr[32];
#pragma unroll
      for (int q4 = 0; q4 < 8; ++q4) *(float4*)&qr[q4 * 4] = *(const float4*)&qsh[r][jq * 32 + q4 * 4];
      const __half* Uep = Ue + ((size_t)(rbase + r) * TT) * HD + jq * 32;
#pragma unroll
      for (int i2 = 0; i2 < 2; ++i2) {
        int t = tl + i2 * 128;
        if (t < TT) {
          const H8* up = (const H8*)(Uep + (size_t)t * HD);
          float sp = 0.f;
#pragma unroll
          for (int c8 = 0; c8 < 4; ++c8) {
            H8 hv = up[c8];
            float2 f0 = __half22float2(hv.a);
            float2 f1 = __half22float2(hv.b);
            float2 f2 = __half22float2(hv.c);
            float2 f3 = __half22float2(hv.d);
            int b0 = c8 * 8;
            sp = fmaf(tanh_f(f0.x + qr[b0 + 0]), vr[b0 + 0], sp);
            sp = fmaf(tanh_f(f0.y + qr[b0 + 1]), vr[b0 + 1], sp);
            sp = fmaf(tanh_f(f1.x + qr[b0 + 2]), vr[b0 + 2], sp);
            sp = fmaf(tanh_f(f1.y + qr[b0 + 3]), vr[b0 + 3], sp);
            sp = fmaf(tanh_f(f2.x + qr[b0 + 4]), vr[b0 + 4], sp);
            sp = fmaf(tanh_f(f2.y + qr[b0 + 5]), vr[b0 + 5], sp);
            sp = fmaf(tanh_f(f3.x + qr[b0 + 6]), vr[b0 + 6], sp);
            sp = fmaf(tanh_f(f3.y + qr[b0 + 7]), vr[b0 + 7], sp);
          }
          sp += __shfl_xor(sp, 1);
          sp += __shfl_xor(sp, 2);
          if (jq == 0) ssh[r][t] = sp;
        }
      }
    }
    __syncthreads();
    // (c) softmax over t (rows 0..3, 32 lanes each)
    if (tid < 128) {
      int r = tid >> 5, l = tid & 31;
      float m = -1e30f;
      for (int t = l; t < TT; t += 32) m = fmaxf(m, ssh[r][t]);
#pragma unroll
      for (int o = 1; o < 32; o <<= 1) m = fmaxf(m, __shfl_xor(m, o, 32));
      float se = 0.f;
      for (int t = l; t < TT; t += 32) { float e = __expf(ssh[r][t] - m); ssh[r][t] = e; se += e; }
#pragma unroll
      for (int o = 1; o < 32; o <<= 1) se += __shfl_xor(se, o, 32);
      float inv = 1.f / se;
      for (int t = l; t < TT; t += 32) ssh[r][t] *= inv;
    }
    __syncthreads();
    // (d) context partials: thread = (jp, r, th); th splits t-range
    {
      int jp = tid & 63, r = (tid >> 6) & 3, th = tid >> 8;
      int t0 = th * 84, t1 = t0 + 84;
      const __half2* ep = (const __half2*)(enc_f16 + ((size_t)(rbase + r) * TT) * HD) + jp;
      float c0 = 0.f, c1 = 0.f;
#pragma unroll 4
      for (int t = t0; t < t1; ++t) {
        float a = ssh[r][t];
        float2 ef = __half22float2(ep[(size_t)t * 64]);
        c0 = fmaf(a, ef.x, c0);
        c1 = fmaf(a, ef.y, c1);
      }
      cpart[th][r][2 * jp] = c0;
      cpart[th][r][2 * jp + 1] = c1;
    }
    __syncthreads();
    // (d2) combine halves -> inp[1+j][r]
    {
      int k = tid & 127, r = tid >> 7;
      inp[1 + k][r] = cpart[0][r][k] + cpart[1][r][k];
    }
    __syncthreads();
    // (e) gates = [din|ctx|h] @ WdT + bias   (thread = gate g)
    {
      float a0 = biasd, a1 = biasd, a2 = biasd, a3 = biasd;
#pragma unroll 4
      for (int k = 0; k < 257; ++k) {
        float w = WdT[k * G4 + g];
        float4 iv = *(const float4*)&inp[k][0];
        a0 = fmaf(iv.x, w, a0);
        a1 = fmaf(iv.y, w, a1);
        a2 = fmaf(iv.z, w, a2);
        a3 = fmaf(iv.w, w, a3);
      }
      if (gty == 2) {
        gsh[g][0] = tanh_f(a0); gsh[g][1] = tanh_f(a1); gsh[g][2] = tanh_f(a2); gsh[g][3] = tanh_f(a3);
      } else {
        gsh[g][0] = sigm_f(a0); gsh[g][1] = sigm_f(a1); gsh[g][2] = sigm_f(a2); gsh[g][3] = sigm_f(a3);
      }
    }
    __syncthreads();
    // (f) cell update + fc partial  (thread = (hidx, rq); row rq)
    {
      float iv = gsh[hidx][rq], fv = gsh[128 + hidx][rq], gv = gsh[256 + hidx][rq], ov = gsh[384 + hidx][rq];
      float c = fmaf(fv, cs[rq][hidx], iv * gv);
      cs[rq][hidx] = c;
      float h2 = ov * tanh_f(c);
      inp[129 + hidx][rq] = h2;
      float sv = h2 * fcw;
#pragma unroll
      for (int o = 1; o < 64; o <<= 1) sv += __shfl_xor(sv, o);
      if ((tid & 63) == 0) ppart[rq][(tid >> 6) & 1] = sv;
    }
    __syncthreads();
    if (tid < RPBD) {
      float pred = ppart[tid][0] + ppart[tid][1] + fcb;
      out[(size_t)(rbase + tid) * OUTH + s] = pred;
      inp[0][tid] = pred;
    }
    __syncthreads();
  }
}

extern "C" void kernel_launch(void* const* d_in, const int* in_sizes, int n_in,
                              void* d_out, int out_size, void* d_ws, size_t ws_size,
                              hipStream_t stream) {
  const float* x       = (const float*)d_in[0];
  const float* enc_Wih = (const float*)d_in[1];
  const float* enc_Whh = (const float*)d_in[2];
  const float* enc_bih = (const float*)d_in[3];
  const float* enc_bhh = (const float*)d_in[4];
  const float* Wa      = (const float*)d_in[5];
  const float* Ua      = (const float*)d_in[6];
  const float* va      = (const float*)d_in[7];
  const float* dec_Wih = (const float*)d_in[8];
  const float* dec_Whh = (const float*)d_in[9];
  const float* dec_bih = (const float*)d_in[10];
  const float* dec_bhh = (const float*)d_in[11];
  const float* fc_W    = (const float*)d_in[12];
  const float* fc_b    = (const float*)d_in[13];
  float* out = (float*)d_out;

  char* ws = (char*)d_ws;
  size_t off = 0;
  float* WhhT = (float*)(ws + off); off += (size_t)HD * G4 * 4;
  float* be   = (float*)(ws + off); off += (size_t)G4 * 4;
  float* WdT  = (float*)(ws + off); off += (size_t)257 * G4 * 4;
  float* bd   = (float*)(ws + off); off += (size_t)G4 * 4;
  float* WaT  = (float*)(ws + off); off += (size_t)HD * HD * 4;
  float* UaT  = (float*)(ws + off); off += (size_t)HD * HD * 4;
  float* hn   = (float*)(ws + off); off += (size_t)NB * HD * 4;
  float* cn   = (float*)(ws + off); off += (size_t)NB * HD * 4;
  const size_t rowB = (size_t)TT * HD * 2;  // 43008 B per row (fp16)
  size_t avail = (ws_size > off) ? ws_size - off : 0;
  int CE, CD;
  if (avail >= 2 * (size_t)NB * rowB) {
    CE = NB; CD = NB;
  } else if (avail >= (size_t)NB * rowB + 16 * rowB) {
    CE = NB;
    CD = NB;
    while (CD > 16 && (size_t)NB * rowB + (size_t)CD * rowB > avail) CD >>= 1;
  } else {
    int c = NB;
    while (c > 16 && 2 * (size_t)c * rowB > avail) c >>= 1;
    if (2 * (size_t)c * rowB > avail) return;
    CE = CD = c;
  }
  __half* encb = (__half*)(ws + off);
  __half* ueb  = (__half*)(ws + off + (size_t)CE * rowB);

  prep_kernel<<<dim3(64), dim3(256), 0, stream>>>(enc_Whh, enc_bih, enc_bhh, Wa, Ua,
      dec_Wih, dec_Whh, dec_bih, dec_bhh, WhhT, be, WdT, bd, WaT, UaT);

  if (CE == NB) {
    enc_kernel<<<dim3(NB / RPBE), dim3(512), 0, stream>>>(x, enc_Wih, WhhT, be, encb, hn, cn);
    for (int c0 = 0; c0 < NB; c0 += CD) {
      const __half* ec = encb + (size_t)c0 * TT * HD;
      ue_kernel<<<dim3(CD * TT / 64), dim3(256), 0, stream>>>(ec, UaT, ueb);
      dec_kernel<<<dim3(CD / RPBD), dim3(512), 0, stream>>>(x + (size_t)c0 * TT, ec, ueb,
          hn + (size_t)c0 * HD, cn + (size_t)c0 * HD, WaT, va, WdT, bd, fc_W, fc_b,
          out + (size_t)c0 * OUTH);
    }
  } else {
    for (int c0 = 0; c0 < NB; c0 += CE) {
      enc_kernel<<<dim3(CE / RPBE), dim3(512), 0, stream>>>(x + (size_t)c0 * TT, enc_Wih, WhhT, be,
          encb, hn + (size_t)c0 * HD, cn + (size_t)c0 * HD);
      ue_kernel<<<dim3(CE * TT / 64), dim3(256), 0, stream>>>(encb, UaT, ueb);
      dec_kernel<<<dim3(CE / RPBD), dim3(512), 0, stream>>>(x + (size_t)c0 * TT, encb, ueb,
          hn + (size_t)c0 * HD, cn + (size_t)c0 * HD, WaT, va, WdT, bd, fc_W, fc_b,
          out + (size_t)c0 * OUTH);
    }
  }
}